// Round 3
// baseline (638.584 us; speedup 1.0000x reference)
//
#include <hip/hip_runtime.h>
#include <hip/hip_bf16.h>

// Mapper: 4 per-word GEMM layers with LN+LeakyReLU between.
// Round 3: BK=64 (8 MFMA/wave/step), 2-deep register prefetch (loads issued
// 2 iterations ahead of LDS write), hw cvt_pk for bf16 pack.

typedef unsigned short u16;
typedef __attribute__((ext_vector_type(8))) short bf16x8;
typedef __attribute__((ext_vector_type(4))) float f32x4;

constexpr int CB = 256;      // batch
constexpr int CW = 20;       // words
constexpr int CDIN = 1024;
constexpr int CDOUT = 1024;
constexpr int CH = 1280;
constexpr float CEPS = 1e-5f;
constexpr float CSLOPE = 0.01f;

// fp32 -> bf16 round-to-nearest-even (scalar, for LN/epilogue paths)
__device__ __forceinline__ u16 f2bf(float f) {
    union { float f; unsigned u; } v; v.f = f;
    unsigned r = v.u + 0x7fffu + ((v.u >> 16) & 1u);
    return (u16)(r >> 16);
}
// packed pair via HW v_cvt_pk_bf16_f32 (through HIP intrinsic)
__device__ __forceinline__ unsigned pk2(float a, float b) {
    __hip_bfloat162 h = __float22bfloat162_rn(float2{a, b});
    union { __hip_bfloat162 h; unsigned u; } v; v.h = h;
    return v.u;
}

// ---------------------------------------------------------------------------
// GEMM: out[b, w, n] = sum_k A[b, w, k] * Bw[w, k, n] + bias[w, n]
// A: bf16 (u16) or fp32 (AF32), row (b*CW+w), K-contiguous.
// Bw: fp32 [W][K][N]. Out: fp32.
// Tile: BM=64, BN=64, BK=64. 256 threads = 4 waves (2x2), each wave 32x32
// = 2x2 MFMA 16x16x32 tiles x 2 k-chunks = 8 MFMA/step.
// LDS rows K-contiguous, stride 72 u16. Double-buffered LDS + 2-deep
// register prefetch: global loads for step k+2 issue at step k.
// Grid: 4 * (N/64) * CW blocks, XCD-swizzled, mb fastest (weight L2 reuse).
// ---------------------------------------------------------------------------
template <int K, int N, bool AF32>
__global__ __launch_bounds__(256, 4) void gemm_kernel(
    const void* __restrict__ Aptr, const float* __restrict__ Bw,
    const float* __restrict__ bias, float* __restrict__ Out)
{
    constexpr int NB  = N / 64;
    constexpr int NK  = K / 64;          // 64-wide K steps (16 or 20, even)
    constexpr int NWG = 4 * NB * CW;
    constexpr int CPX = NWG / 8;

    __shared__ u16 As[2][64 * 72];
    __shared__ u16 Bs[2][64 * 72];

    const int t   = threadIdx.x;
    const int bid = blockIdx.x;
    const int logical = (bid & 7) * CPX + (bid >> 3);
    const int mb = logical & 3;
    const int nb = (logical >> 2) % NB;
    const int w  = logical / (4 * NB);

    const int m0g = mb * 64;
    const int n0g = nb * 64;

    const int lane = t & 63;
    const int wid  = t >> 6;
    const int m0 = (wid >> 1) * 32;
    const int n0 = (wid & 1) * 32;
    const int lrow = lane & 15;
    const int kg   = lane >> 4;           // 0..3, k-chunk of 8

    // A staging: thread -> (row = t>>2, 16 k-elems at (t&3)*16)
    const int ar = t >> 2;
    const int ac = (t & 3) * 16;
    const u16*   agp  = (const u16*)Aptr   + ((size_t)(m0g + ar) * CW + w) * K + ac;
    const float* agpf = (const float*)Aptr + ((size_t)(m0g + ar) * CW + w) * K + ac;

    // B staging: thread -> (n = t&63, 16 k-rows at (t>>6)*16)
    const int bn = t & 63;
    const int bq = t >> 6;
    const float* bgp = Bw + (size_t)w * K * N + (size_t)bq * 16 * N + (n0g + bn);

    f32x4 acc[2][2];
    #pragma unroll
    for (int i = 0; i < 2; ++i)
        #pragma unroll
        for (int j = 0; j < 2; ++j)
            acc[i][j] = (f32x4){0.f, 0.f, 0.f, 0.f};

    // two named prefetch slots (statically indexed everywhere)
    uint4  a_s0[2], a_s1[2];
    float4 af_s0[4], af_s1[4];
    float  b_s0[16], b_s1[16];

#define LOADA(k0, SL)                                                         \
    do {                                                                      \
        if constexpr (AF32) {                                                 \
            const float4* p = reinterpret_cast<const float4*>(agpf + (k0));   \
            af_s##SL[0] = p[0]; af_s##SL[1] = p[1];                           \
            af_s##SL[2] = p[2]; af_s##SL[3] = p[3];                           \
        } else {                                                              \
            const uint4* p = reinterpret_cast<const uint4*>(agp + (k0));      \
            a_s##SL[0] = p[0]; a_s##SL[1] = p[1];                             \
        }                                                                     \
    } while (0)

#define LOADB(k0, SL)                                                         \
    do {                                                                      \
        const float* p = bgp + (size_t)(k0) * N;                              \
        _Pragma("unroll")                                                     \
        for (int i = 0; i < 16; ++i) b_s##SL[i] = p[(size_t)i * N];           \
    } while (0)

#define WRITEA(buf, SL)                                                       \
    do {                                                                      \
        if constexpr (AF32) {                                                 \
            uint4 q0, q1;                                                     \
            q0.x = pk2(af_s##SL[0].x, af_s##SL[0].y);                         \
            q0.y = pk2(af_s##SL[0].z, af_s##SL[0].w);                         \
            q0.z = pk2(af_s##SL[1].x, af_s##SL[1].y);                         \
            q0.w = pk2(af_s##SL[1].z, af_s##SL[1].w);                         \
            q1.x = pk2(af_s##SL[2].x, af_s##SL[2].y);                         \
            q1.y = pk2(af_s##SL[2].z, af_s##SL[2].w);                         \
            q1.z = pk2(af_s##SL[3].x, af_s##SL[3].y);                         \
            q1.w = pk2(af_s##SL[3].z, af_s##SL[3].w);                         \
            *reinterpret_cast<uint4*>(&As[buf][ar * 72 + ac])     = q0;       \
            *reinterpret_cast<uint4*>(&As[buf][ar * 72 + ac + 8]) = q1;       \
        } else {                                                              \
            *reinterpret_cast<uint4*>(&As[buf][ar * 72 + ac])     = a_s##SL[0]; \
            *reinterpret_cast<uint4*>(&As[buf][ar * 72 + ac + 8]) = a_s##SL[1]; \
        }                                                                     \
    } while (0)

#define WRITEB(buf, SL)                                                       \
    do {                                                                      \
        uint4 q0, q1;                                                         \
        q0.x = pk2(b_s##SL[0],  b_s##SL[1]);                                  \
        q0.y = pk2(b_s##SL[2],  b_s##SL[3]);                                  \
        q0.z = pk2(b_s##SL[4],  b_s##SL[5]);                                  \
        q0.w = pk2(b_s##SL[6],  b_s##SL[7]);                                  \
        q1.x = pk2(b_s##SL[8],  b_s##SL[9]);                                  \
        q1.y = pk2(b_s##SL[10], b_s##SL[11]);                                 \
        q1.z = pk2(b_s##SL[12], b_s##SL[13]);                                 \
        q1.w = pk2(b_s##SL[14], b_s##SL[15]);                                 \
        *reinterpret_cast<uint4*>(&Bs[buf][bn * 72 + bq * 16])     = q0;      \
        *reinterpret_cast<uint4*>(&Bs[buf][bn * 72 + bq * 16 + 8]) = q1;      \
    } while (0)

    auto compute = [&](int buf) {
        #pragma unroll
        for (int kc = 0; kc < 2; ++kc) {
            bf16x8 af[2], bf[2];
            #pragma unroll
            for (int i = 0; i < 2; ++i)
                af[i] = *reinterpret_cast<const bf16x8*>(
                    &As[buf][(m0 + i * 16 + lrow) * 72 + kc * 32 + kg * 8]);
            #pragma unroll
            for (int j = 0; j < 2; ++j)
                bf[j] = *reinterpret_cast<const bf16x8*>(
                    &Bs[buf][(n0 + j * 16 + lrow) * 72 + kc * 32 + kg * 8]);
            #pragma unroll
            for (int i = 0; i < 2; ++i)
                #pragma unroll
                for (int j = 0; j < 2; ++j)
                    acc[i][j] = __builtin_amdgcn_mfma_f32_16x16x32_bf16(
                        af[i], bf[j], acc[i][j], 0, 0, 0);
        }
    };

    // prologue: slots 0,1 <- steps 0,1; LDS buf0 <- step 0
    LOADA(0, 0); LOADB(0, 0);
    LOADA(64, 1); LOADB(64, 1);
    WRITEA(0, 0); WRITEB(0, 0);
    __syncthreads();

    for (int ks = 0; ks < NK; ks += 2) {
        if (ks + 2 < NK) { LOADA((ks + 2) * 64, 0); LOADB((ks + 2) * 64, 0); }
        compute(0);
        if (ks + 1 < NK) { WRITEA(1, 1); WRITEB(1, 1); }
        __syncthreads();

        if (ks + 3 < NK) { LOADA((ks + 3) * 64, 1); LOADB((ks + 3) * 64, 1); }
        compute(1);
        if (ks + 2 < NK) { WRITEA(0, 0); WRITEB(0, 0); }
        __syncthreads();
    }

    // epilogue: + bias, store fp32
    const int rb = (lane >> 4) * 4;
    #pragma unroll
    for (int j = 0; j < 2; ++j) {
        const int gn = n0g + n0 + j * 16 + lrow;
        const float bv = bias[(size_t)w * N + gn];
        #pragma unroll
        for (int i = 0; i < 2; ++i) {
            const int gm = m0g + m0 + i * 16 + rb;
            #pragma unroll
            for (int r = 0; r < 4; ++r) {
                Out[((size_t)(gm + r) * CW + w) * N + gn] = acc[i][j][r] + bv;
            }
        }
    }
#undef LOADA
#undef LOADB
#undef WRITEA
#undef WRITEB
}

// ---------------------------------------------------------------------------
// LayerNorm + LeakyReLU over last dim (H=1280), writes bf16.
// One block (320 threads, 5 waves) per row; each thread one float4.
// ---------------------------------------------------------------------------
__global__ __launch_bounds__(320) void ln_lrelu_kernel(
    const float* __restrict__ h, const float* __restrict__ g,
    const float* __restrict__ bta, u16* __restrict__ out)
{
    const int row = blockIdx.x;          // b*CW + w
    const int w = row % CW;
    const int t = threadIdx.x;

    const float4 v = reinterpret_cast<const float4*>(h + (size_t)row * CH)[t];
    float s  = v.x + v.y + v.z + v.w;
    float sq = v.x * v.x + v.y * v.y + v.z * v.z + v.w * v.w;
    #pragma unroll
    for (int o = 32; o > 0; o >>= 1) {
        s  += __shfl_down(s, o, 64);
        sq += __shfl_down(sq, o, 64);
    }
    __shared__ float ss[5], sg[5];
    const int lane = t & 63, wv = t >> 6;
    if (lane == 0) { ss[wv] = s; sg[wv] = sq; }
    __syncthreads();
    float S = 0.f, Q = 0.f;
    #pragma unroll
    for (int i = 0; i < 5; ++i) { S += ss[i]; Q += sg[i]; }
    const float mean = S * (1.0f / CH);
    const float var  = Q * (1.0f / CH) - mean * mean;
    const float rstd = rsqrtf(var + CEPS);

    const float4 gg = reinterpret_cast<const float4*>(g   + (size_t)w * CH)[t];
    const float4 bb = reinterpret_cast<const float4*>(bta + (size_t)w * CH)[t];
    float4 y;
    y.x = (v.x - mean) * rstd * gg.x + bb.x;
    y.y = (v.y - mean) * rstd * gg.y + bb.y;
    y.z = (v.z - mean) * rstd * gg.z + bb.z;
    y.w = (v.w - mean) * rstd * gg.w + bb.w;
    y.x = y.x >= 0.f ? y.x : CSLOPE * y.x;
    y.y = y.y >= 0.f ? y.y : CSLOPE * y.y;
    y.z = y.z >= 0.f ? y.z : CSLOPE * y.z;
    y.w = y.w >= 0.f ? y.w : CSLOPE * y.w;
    ushort4 o4;
    o4.x = f2bf(y.x); o4.y = f2bf(y.y); o4.z = f2bf(y.z); o4.w = f2bf(y.w);
    reinterpret_cast<ushort4*>(out + (size_t)row * CH)[t] = o4;
}

extern "C" void kernel_launch(void* const* d_in, const int* in_sizes, int n_in,
                              void* d_out, int out_size, void* d_ws, size_t ws_size,
                              hipStream_t stream)
{
    const float* embs = (const float*)d_in[0];
    const float* W1  = (const float*)d_in[1];
    const float* b1  = (const float*)d_in[2];
    const float* g1  = (const float*)d_in[3];
    const float* bn1 = (const float*)d_in[4];
    const float* W2  = (const float*)d_in[5];
    const float* b2  = (const float*)d_in[6];
    const float* g2  = (const float*)d_in[7];
    const float* bn2 = (const float*)d_in[8];
    const float* W3  = (const float*)d_in[9];
    const float* b3  = (const float*)d_in[10];
    const float* g3  = (const float*)d_in[11];
    const float* bn3 = (const float*)d_in[12];
    const float* W4  = (const float*)d_in[13];
    const float* b4  = (const float*)d_in[14];

    char* ws = (char*)d_ws;
    float* h_raw = (float*)ws;                               // B*W*H*4  = 26,214,400
    u16*   a_bf  = (u16*)(ws + 26214400);                    // B*W*H*2  = 13,107,200

    // Layer 1: [256x1024] @ [1024x1280], A = embs fp32 (converted in staging)
    gemm_kernel<CDIN, CH, true><<<4 * (CH / 64) * CW, 256, 0, stream>>>(embs, W1, b1, h_raw);
    ln_lrelu_kernel<<<CB * CW, 320, 0, stream>>>(h_raw, g1, bn1, a_bf);
    // Layer 2: [256x1280] @ [1280x1280]
    gemm_kernel<CH, CH, false><<<4 * (CH / 64) * CW, 256, 0, stream>>>(a_bf, W2, b2, h_raw);
    ln_lrelu_kernel<<<CB * CW, 320, 0, stream>>>(h_raw, g2, bn2, a_bf);
    // Layer 3: [256x1280] @ [1280x1280]
    gemm_kernel<CH, CH, false><<<4 * (CH / 64) * CW, 256, 0, stream>>>(a_bf, W3, b3, h_raw);
    ln_lrelu_kernel<<<CB * CW, 320, 0, stream>>>(h_raw, g3, bn3, a_bf);
    // Layer 4: [256x1280] @ [1280x1024] -> d_out (fp32)
    gemm_kernel<CH, CDOUT, false><<<4 * (CDOUT / 64) * CW, 256, 0, stream>>>(a_bf, W4, b4, (float*)d_out);
}

// Round 4
// 271.123 us; speedup vs baseline: 2.3553x; 2.3553x over previous
//
#include <hip/hip_runtime.h>
#include <hip/hip_bf16.h>

// Mapper: 4 per-word GEMM layers with LN+LeakyReLU between.
// Round 4: BK=64 + depth-2 register prefetch, spill fix (launch_bounds(256,2),
// fully static staging indices). Layer 1 (fp32 A) uses depth-1.

typedef unsigned short u16;
typedef __attribute__((ext_vector_type(8))) short bf16x8;
typedef __attribute__((ext_vector_type(4))) float f32x4;

constexpr int CB = 256;      // batch
constexpr int CW = 20;       // words
constexpr int CDIN = 1024;
constexpr int CDOUT = 1024;
constexpr int CH = 1280;
constexpr float CEPS = 1e-5f;
constexpr float CSLOPE = 0.01f;

__device__ __forceinline__ u16 f2bf(float f) {
    union { float f; unsigned u; } v; v.f = f;
    unsigned r = v.u + 0x7fffu + ((v.u >> 16) & 1u);
    return (u16)(r >> 16);
}
// packed pair via HW v_cvt_pk_bf16_f32
__device__ __forceinline__ unsigned pk2(float a, float b) {
    __hip_bfloat162 h = __float22bfloat162_rn(float2{a, b});
    union { __hip_bfloat162 h; unsigned u; } v; v.h = h;
    return v.u;
}

// ---------------------------------------------------------------------------
// GEMM: out[b, w, n] = sum_k A[b, w, k] * Bw[w, k, n] + bias[w, n]
// A: bf16 (u16) or fp32 (AF32), row (b*CW+w), K-contiguous.
// Bw: fp32 [W][K][N]. Out: fp32.
// Tile: BM=64, BN=64, BK=64. 256 threads = 4 waves (2x2), wave = 32x32
// = 2x2 MFMA 16x16x32 x 2 k-chunks = 8 MFMA/step.
// bf16 path: depth-2 register prefetch (slot loads issued 2 LDS-steps ahead;
// compiler emits counted vmcnt since the other slot's loads stay in flight).
// AF32 path (layer 1 only): depth-1.
// LDS rows K-contiguous, stride 72 u16. Grid XCD-swizzled, mb fastest.
// ---------------------------------------------------------------------------
template <int K, int N, bool AF32>
__global__ __launch_bounds__(256, 2) void gemm_kernel(
    const void* __restrict__ Aptr, const float* __restrict__ Bw,
    const float* __restrict__ bias, float* __restrict__ Out)
{
    constexpr int NB  = N / 64;
    constexpr int NK  = K / 64;          // 16 or 20, even
    constexpr int NWG = 4 * NB * CW;
    constexpr int CPX = NWG / 8;

    __shared__ u16 As[2][64 * 72];
    __shared__ u16 Bs[2][64 * 72];

    const int t   = threadIdx.x;
    const int bid = blockIdx.x;
    const int logical = (bid & 7) * CPX + (bid >> 3);
    const int mb = logical & 3;
    const int nb = (logical >> 2) % NB;
    const int w  = logical / (4 * NB);

    const int m0g = mb * 64;
    const int n0g = nb * 64;

    const int lane = t & 63;
    const int wid  = t >> 6;
    const int m0 = (wid >> 1) * 32;
    const int n0 = (wid & 1) * 32;
    const int lrow = lane & 15;
    const int kg   = lane >> 4;

    // A staging: thread -> (row = t>>2, 16 k-elems at (t&3)*16)
    const int ar = t >> 2;
    const int ac = (t & 3) * 16;
    const u16*   agp  = (const u16*)Aptr   + ((size_t)(m0g + ar) * CW + w) * K + ac;
    const float* agpf = (const float*)Aptr + ((size_t)(m0g + ar) * CW + w) * K + ac;

    // B staging: thread -> (n = t&63, 16 k-rows at (t>>6)*16), dword stride N
    const int bn = t & 63;
    const int bq = t >> 6;
    const float* bgp = Bw + (size_t)w * K * N + (size_t)bq * 16 * N + (n0g + bn);

    f32x4 acc[2][2];
    #pragma unroll
    for (int i = 0; i < 2; ++i)
        #pragma unroll
        for (int j = 0; j < 2; ++j)
            acc[i][j] = (f32x4){0.f, 0.f, 0.f, 0.f};

    // prefetch slots — every access below is a static index
    uint4  a_s0_0, a_s0_1, a_s1_0, a_s1_1;
    float4 af_s0_0, af_s0_1, af_s0_2, af_s0_3;
    float  b_s0_0, b_s0_1, b_s0_2,  b_s0_3,  b_s0_4,  b_s0_5,  b_s0_6,  b_s0_7;
    float  b_s0_8, b_s0_9, b_s0_10, b_s0_11, b_s0_12, b_s0_13, b_s0_14, b_s0_15;
    float  b_s1_0, b_s1_1, b_s1_2,  b_s1_3,  b_s1_4,  b_s1_5,  b_s1_6,  b_s1_7;
    float  b_s1_8, b_s1_9, b_s1_10, b_s1_11, b_s1_12, b_s1_13, b_s1_14, b_s1_15;

#define LOADA_BF(k0, SL)                                                      \
    do {                                                                      \
        const uint4* p = reinterpret_cast<const uint4*>(agp + (k0));          \
        a_s##SL##_0 = p[0]; a_s##SL##_1 = p[1];                               \
    } while (0)

#define LOADA_F32(k0)                                                         \
    do {                                                                      \
        const float4* p = reinterpret_cast<const float4*>(agpf + (k0));       \
        af_s0_0 = p[0]; af_s0_1 = p[1]; af_s0_2 = p[2]; af_s0_3 = p[3];       \
    } while (0)

#define LOADB(k0, SL)                                                         \
    do {                                                                      \
        const float* p = bgp + (size_t)(k0) * N;                              \
        b_s##SL##_0  = p[0];                 b_s##SL##_1  = p[(size_t)1 * N]; \
        b_s##SL##_2  = p[(size_t)2 * N];     b_s##SL##_3  = p[(size_t)3 * N]; \
        b_s##SL##_4  = p[(size_t)4 * N];     b_s##SL##_5  = p[(size_t)5 * N]; \
        b_s##SL##_6  = p[(size_t)6 * N];     b_s##SL##_7  = p[(size_t)7 * N]; \
        b_s##SL##_8  = p[(size_t)8 * N];     b_s##SL##_9  = p[(size_t)9 * N]; \
        b_s##SL##_10 = p[(size_t)10 * N];    b_s##SL##_11 = p[(size_t)11 * N];\
        b_s##SL##_12 = p[(size_t)12 * N];    b_s##SL##_13 = p[(size_t)13 * N];\
        b_s##SL##_14 = p[(size_t)14 * N];    b_s##SL##_15 = p[(size_t)15 * N];\
    } while (0)

#define WRITEA_BF(buf, SL)                                                    \
    do {                                                                      \
        *reinterpret_cast<uint4*>(&As[buf][ar * 72 + ac])     = a_s##SL##_0;  \
        *reinterpret_cast<uint4*>(&As[buf][ar * 72 + ac + 8]) = a_s##SL##_1;  \
    } while (0)

#define WRITEA_F32(buf)                                                       \
    do {                                                                      \
        uint4 q0, q1;                                                         \
        q0.x = pk2(af_s0_0.x, af_s0_0.y); q0.y = pk2(af_s0_0.z, af_s0_0.w);   \
        q0.z = pk2(af_s0_1.x, af_s0_1.y); q0.w = pk2(af_s0_1.z, af_s0_1.w);   \
        q1.x = pk2(af_s0_2.x, af_s0_2.y); q1.y = pk2(af_s0_2.z, af_s0_2.w);   \
        q1.z = pk2(af_s0_3.x, af_s0_3.y); q1.w = pk2(af_s0_3.z, af_s0_3.w);   \
        *reinterpret_cast<uint4*>(&As[buf][ar * 72 + ac])     = q0;           \
        *reinterpret_cast<uint4*>(&As[buf][ar * 72 + ac + 8]) = q1;           \
    } while (0)

#define WRITEB(buf, SL)                                                       \
    do {                                                                      \
        uint4 q0, q1;                                                         \
        q0.x = pk2(b_s##SL##_0,  b_s##SL##_1);                                \
        q0.y = pk2(b_s##SL##_2,  b_s##SL##_3);                                \
        q0.z = pk2(b_s##SL##_4,  b_s##SL##_5);                                \
        q0.w = pk2(b_s##SL##_6,  b_s##SL##_7);                                \
        q1.x = pk2(b_s##SL##_8,  b_s##SL##_9);                                \
        q1.y = pk2(b_s##SL##_10, b_s##SL##_11);                               \
        q1.z = pk2(b_s##SL##_12, b_s##SL##_13);                               \
        q1.w = pk2(b_s##SL##_14, b_s##SL##_15);                               \
        *reinterpret_cast<uint4*>(&Bs[buf][bn * 72 + bq * 16])     = q0;      \
        *reinterpret_cast<uint4*>(&Bs[buf][bn * 72 + bq * 16 + 8]) = q1;      \
    } while (0)

    auto compute = [&](int buf) {
        #pragma unroll
        for (int kc = 0; kc < 2; ++kc) {
            bf16x8 af[2], bf[2];
            #pragma unroll
            for (int i = 0; i < 2; ++i)
                af[i] = *reinterpret_cast<const bf16x8*>(
                    &As[buf][(m0 + i * 16 + lrow) * 72 + kc * 32 + kg * 8]);
            #pragma unroll
            for (int j = 0; j < 2; ++j)
                bf[j] = *reinterpret_cast<const bf16x8*>(
                    &Bs[buf][(n0 + j * 16 + lrow) * 72 + kc * 32 + kg * 8]);
            #pragma unroll
            for (int i = 0; i < 2; ++i)
                #pragma unroll
                for (int j = 0; j < 2; ++j)
                    acc[i][j] = __builtin_amdgcn_mfma_f32_16x16x32_bf16(
                        af[i], bf[j], acc[i][j], 0, 0, 0);
        }
    };

    if constexpr (AF32) {
        // depth-1 pipeline (fp32 A staging is register-heavy)
        LOADA_F32(0); LOADB(0, 0);
        WRITEA_F32(0); WRITEB(0, 0);
        __syncthreads();
        int buf = 0;
        for (int ks = 0; ks < NK; ++ks) {
            if (ks + 1 < NK) { LOADA_F32((ks + 1) * 64); LOADB((ks + 1) * 64, 0); }
            compute(buf);
            if (ks + 1 < NK) { WRITEA_F32(buf ^ 1); WRITEB(buf ^ 1, 0); }
            __syncthreads();
            buf ^= 1;
        }
    } else {
        // depth-2 pipeline
        LOADA_BF(0, 0);  LOADB(0, 0);
        LOADA_BF(64, 1); LOADB(64, 1);
        WRITEA_BF(0, 0); WRITEB(0, 0);
        __syncthreads();
        for (int ks = 0; ks < NK; ks += 2) {
            if (ks + 2 < NK) { LOADA_BF((ks + 2) * 64, 0); LOADB((ks + 2) * 64, 0); }
            compute(0);
            if (ks + 1 < NK) { WRITEA_BF(1, 1); WRITEB(1, 1); }
            __syncthreads();

            if (ks + 3 < NK) { LOADA_BF((ks + 3) * 64, 1); LOADB((ks + 3) * 64, 1); }
            compute(1);
            if (ks + 2 < NK) { WRITEA_BF(0, 0); WRITEB(0, 0); }
            __syncthreads();
        }
    }

    // epilogue: + bias, store fp32
    const int rb = (lane >> 4) * 4;
    #pragma unroll
    for (int j = 0; j < 2; ++j) {
        const int gn = n0g + n0 + j * 16 + lrow;
        const float bv = bias[(size_t)w * N + gn];
        #pragma unroll
        for (int i = 0; i < 2; ++i) {
            const int gm = m0g + m0 + i * 16 + rb;
            #pragma unroll
            for (int r = 0; r < 4; ++r) {
                Out[((size_t)(gm + r) * CW + w) * N + gn] = acc[i][j][r] + bv;
            }
        }
    }
#undef LOADA_BF
#undef LOADA_F32
#undef LOADB
#undef WRITEA_BF
#undef WRITEA_F32
#undef WRITEB
}

// ---------------------------------------------------------------------------
// LayerNorm + LeakyReLU over last dim (H=1280), writes bf16.
// ---------------------------------------------------------------------------
__global__ __launch_bounds__(320) void ln_lrelu_kernel(
    const float* __restrict__ h, const float* __restrict__ g,
    const float* __restrict__ bta, u16* __restrict__ out)
{
    const int row = blockIdx.x;          // b*CW + w
    const int w = row % CW;
    const int t = threadIdx.x;

    const float4 v = reinterpret_cast<const float4*>(h + (size_t)row * CH)[t];
    float s  = v.x + v.y + v.z + v.w;
    float sq = v.x * v.x + v.y * v.y + v.z * v.z + v.w * v.w;
    #pragma unroll
    for (int o = 32; o > 0; o >>= 1) {
        s  += __shfl_down(s, o, 64);
        sq += __shfl_down(sq, o, 64);
    }
    __shared__ float ss[5], sg[5];
    const int lane = t & 63, wv = t >> 6;
    if (lane == 0) { ss[wv] = s; sg[wv] = sq; }
    __syncthreads();
    float S = 0.f, Q = 0.f;
    #pragma unroll
    for (int i = 0; i < 5; ++i) { S += ss[i]; Q += sg[i]; }
    const float mean = S * (1.0f / CH);
    const float var  = Q * (1.0f / CH) - mean * mean;
    const float rstd = rsqrtf(var + CEPS);

    const float4 gg = reinterpret_cast<const float4*>(g   + (size_t)w * CH)[t];
    const float4 bb = reinterpret_cast<const float4*>(bta + (size_t)w * CH)[t];
    float4 y;
    y.x = (v.x - mean) * rstd * gg.x + bb.x;
    y.y = (v.y - mean) * rstd * gg.y + bb.y;
    y.z = (v.z - mean) * rstd * gg.z + bb.z;
    y.w = (v.w - mean) * rstd * gg.w + bb.w;
    y.x = y.x >= 0.f ? y.x : CSLOPE * y.x;
    y.y = y.y >= 0.f ? y.y : CSLOPE * y.y;
    y.z = y.z >= 0.f ? y.z : CSLOPE * y.z;
    y.w = y.w >= 0.f ? y.w : CSLOPE * y.w;
    ushort4 o4;
    o4.x = f2bf(y.x); o4.y = f2bf(y.y); o4.z = f2bf(y.z); o4.w = f2bf(y.w);
    reinterpret_cast<ushort4*>(out + (size_t)row * CH)[t] = o4;
}

extern "C" void kernel_launch(void* const* d_in, const int* in_sizes, int n_in,
                              void* d_out, int out_size, void* d_ws, size_t ws_size,
                              hipStream_t stream)
{
    const float* embs = (const float*)d_in[0];
    const float* W1  = (const float*)d_in[1];
    const float* b1  = (const float*)d_in[2];
    const float* g1  = (const float*)d_in[3];
    const float* bn1 = (const float*)d_in[4];
    const float* W2  = (const float*)d_in[5];
    const float* b2  = (const float*)d_in[6];
    const float* g2  = (const float*)d_in[7];
    const float* bn2 = (const float*)d_in[8];
    const float* W3  = (const float*)d_in[9];
    const float* b3  = (const float*)d_in[10];
    const float* g3  = (const float*)d_in[11];
    const float* bn3 = (const float*)d_in[12];
    const float* W4  = (const float*)d_in[13];
    const float* b4  = (const float*)d_in[14];

    char* ws = (char*)d_ws;
    float* h_raw = (float*)ws;                               // B*W*H*4  = 26,214,400
    u16*   a_bf  = (u16*)(ws + 26214400);                    // B*W*H*2  = 13,107,200

    // Layer 1: [256x1024] @ [1024x1280], A = embs fp32 (converted in staging)
    gemm_kernel<CDIN, CH, true><<<4 * (CH / 64) * CW, 256, 0, stream>>>(embs, W1, b1, h_raw);
    ln_lrelu_kernel<<<CB * CW, 320, 0, stream>>>(h_raw, g1, bn1, a_bf);
    // Layer 2: [256x1280] @ [1280x1280]
    gemm_kernel<CH, CH, false><<<4 * (CH / 64) * CW, 256, 0, stream>>>(a_bf, W2, b2, h_raw);
    ln_lrelu_kernel<<<CB * CW, 320, 0, stream>>>(h_raw, g2, bn2, a_bf);
    // Layer 3: [256x1280] @ [1280x1280]
    gemm_kernel<CH, CH, false><<<4 * (CH / 64) * CW, 256, 0, stream>>>(a_bf, W3, b3, h_raw);
    ln_lrelu_kernel<<<CB * CW, 320, 0, stream>>>(h_raw, g3, bn3, a_bf);
    // Layer 4: [256x1280] @ [1280x1024] -> d_out (fp32)
    gemm_kernel<CH, CDOUT, false><<<4 * (CDOUT / 64) * CW, 256, 0, stream>>>(a_bf, W4, b4, (float*)d_out);
}